// Round 14
// baseline (105.640 us; speedup 1.0000x reference)
//
#include <hip/hip_runtime.h>
#include <math.h>

// QuGCN pipeline v13 — THREE launches:
//   K1 build_quarter4w : 1024 blocks x 256 thr (4096 waves = 4/SIMD). Block
//                        (l, s0) simulates basis e_{s0} through LAYER l only
//                        (81-gate chain; M0 fusion carries RZ124 across cuts)
//                        with 1 complex amp per thread. [R12 layout x R5 split]
//   K2 combine_emit    : 512 blocks: T1 = U1*U0 -> U1bf [512x256] bf16,
//                        T2 = U3*U2 -> W2bf [512x512] bf16 [[Re,-Im],[Im,Re]].
//                        [R10-verified verbatim]
//   K3 eval_chain      : 256 blk x 1024 thr: y = T1*x (MFMA) -> Ys LDS,
//                        amps = W2*y (MFMA), fused |amp|^2 -> <Z_q> -> norm
//                        -> linear head. [R8/R13-verified verbatim]

namespace {

constexpr int NSAMP = 4096;
constexpr int NW_L  = 132;

// ---------- compile-time trig ----------
constexpr double PI_D   = 3.14159265358979323846264338327950288;
constexpr double TWO_PI = 6.28318530717958647692528676655900577;

constexpr double red_pm_pi(double x) {
  double k = x / TWO_PI;
  long long ki = (long long)k;
  double r = x - (double)ki * TWO_PI;
  if (r > PI_D)  r -= TWO_PI;
  if (r < -PI_D) r += TWO_PI;
  return r;
}
constexpr double csin(double x) {
  double r = red_pm_pi(x), r2 = r * r, term = r, sum = r;
  for (int n = 1; n <= 13; ++n) { term *= -r2 / (double)((2*n)*(2*n+1)); sum += term; }
  return sum;
}
constexpr double ccos(double x) {
  double r = red_pm_pi(x), r2 = r * r, term = 1.0, sum = 1.0;
  for (int n = 1; n <= 13; ++n) { term *= -r2 / (double)((2*n-1)*(2*n)); sum += term; }
  return sum;
}

constexpr int PC[28] = {0,1,2,3,4,5,6, 0,1,2,3,4,5, 0,1,2,3,4, 0,1,2,3, 0,1,2, 0,1, 0};
constexpr int PT[28] = {1,2,3,4,5,6,7, 2,3,4,5,6,7, 3,4,5,6,7, 4,5,6,7, 5,6,7, 6,7, 7};

struct Tbl28 { float c[28]; float s[28]; };
constexpr Tbl28 mk_tbl(int base) {
  Tbl28 t{};
  for (int i = 0; i < 28; ++i) {
    double a = 0.5 * (double)(base + i);
    t.c[i] = (float)ccos(a);
    t.s[i] = (float)csin(a);
  }
  return t;
}
constexpr Tbl28 T_CRY = mk_tbl(8);
constexpr Tbl28 T_CRX = mk_tbl(52);

struct DTbl { float v[512]; };
constexpr DTbl mk_dcrz() {
  DTbl t{};
  for (int s = 0; s < 256; ++s) {
    double psi = 0.0;
    for (int i = 0; i < 28; ++i) {
      const int pc = 7 - PC[i], pt = 7 - PT[i];
      if ((s >> pc) & 1) {
        const double half = 0.5 * (double)(96 + i);
        psi += ((s >> pt) & 1) ? half : -half;
      }
    }
    t.v[2*s]   = (float)ccos(psi);
    t.v[2*s+1] = (float)csin(psi);
  }
  return t;
}
__device__ constexpr DTbl D_CRZ = mk_dcrz();

// ---------- single-amp cross-lane xor on lane bit p (0..5) [verified R12] ----------
__device__ __forceinline__ float shx1(float v, int p) {
  if (p == 0) {
    int r = __builtin_amdgcn_update_dpp((int)__float_as_uint(v), (int)__float_as_uint(v),
                                        0xB1, 0xF, 0xF, true);
    return __uint_as_float((unsigned)r);
  }
  if (p == 1) {
    int r = __builtin_amdgcn_update_dpp((int)__float_as_uint(v), (int)__float_as_uint(v),
                                        0x4E, 0xF, 0xF, true);
    return __uint_as_float((unsigned)r);
  }
  if (p == 2) return __uint_as_float((unsigned)__builtin_amdgcn_ds_swizzle(
                      (int)__float_as_uint(v), 0x101F));   // xor 4
  if (p == 3) return __uint_as_float((unsigned)__builtin_amdgcn_ds_swizzle(
                      (int)__float_as_uint(v), 0x201F));   // xor 8
  if (p == 4) return __uint_as_float((unsigned)__builtin_amdgcn_ds_swizzle(
                      (int)__float_as_uint(v), 0x401F));   // xor 16
  return __shfl_xor(v, 32, 64);
}

// ---------- single-amp gate appliers [verified R12] ----------
__device__ __forceinline__ void gen_lane(float& ar, float& ai, int s, int p,
                                         float m00r, float m00i, float m01r, float m01i) {
  const int b = (s >> p) & 1;
  const float dr = m00r;
  const float di = b ? -m00i : m00i;
  const float g  = b ? -m01r : m01r;
  const float hh = m01i;
  const float pr = shx1(ar, p);
  const float pi = shx1(ai, p);
  const float mr = ar, mi = ai;
  ar = dr*mr - di*mi + g*pr - hh*pi;
  ai = dr*mi + di*mr + g*pi + hh*pr;
}
__device__ __forceinline__ void gen_xw(float& ar, float& ai, int s, int p,
                                       float m00r, float m00i, float m01r, float m01i,
                                       float2* xbuf) {
  xbuf[s] = make_float2(ar, ai);
  __syncthreads();
  const float2 pt = xbuf[s ^ (1 << p)];
  __syncthreads();
  const int b = (s >> p) & 1;
  const float dr = m00r;
  const float di = b ? -m00i : m00i;
  const float g  = b ? -m01r : m01r;
  const float hh = m01i;
  const float mr = ar, mi = ai;
  ar = dr*mr - di*mi + g*pt.x - hh*pt.y;
  ai = dr*mi + di*mr + g*pt.y + hh*pt.x;
}
__device__ __forceinline__ void cry_lane(float& ar, float& ai, int s, int pc, int pt,
                                         float cc, float sc) {
  const int ctrl = (s >> pc) & 1;
  const float ce = ctrl ? cc : 1.0f;
  float se = ((s >> pt) & 1) ? sc : -sc;
  se = ctrl ? se : 0.0f;
  const float pr = shx1(ar, pt);
  const float pi = shx1(ai, pt);
  ar = ce*ar + se*pr;
  ai = ce*ai + se*pi;
}
__device__ __forceinline__ void cry_xw(float& ar, float& ai, int s, int pc, int pt,
                                       float cc, float sc, float2* xbuf) {
  xbuf[s] = make_float2(ar, ai);
  __syncthreads();
  const float2 p = xbuf[s ^ (1 << pt)];
  __syncthreads();
  const int ctrl = (s >> pc) & 1;
  const float ce = ctrl ? cc : 1.0f;
  float se = ((s >> pt) & 1) ? sc : -sc;
  se = ctrl ? se : 0.0f;
  ar = ce*ar + se*p.x;
  ai = ce*ai + se*p.y;
}
__device__ __forceinline__ void crx_lane(float& ar, float& ai, int s, int pc, int pt,
                                         float cc, float sc) {
  const int ctrl = (s >> pc) & 1;
  const float ce = ctrl ? cc : 1.0f;
  const float se = ctrl ? sc : 0.0f;
  const float pr = shx1(ar, pt);
  const float pi = shx1(ai, pt);
  ar = ce*ar + se*pi;
  ai = ce*ai - se*pr;
}
__device__ __forceinline__ void crx_xw(float& ar, float& ai, int s, int pc, int pt,
                                       float cc, float sc, float2* xbuf) {
  xbuf[s] = make_float2(ar, ai);
  __syncthreads();
  const float2 p = xbuf[s ^ (1 << pt)];
  __syncthreads();
  const int ctrl = (s >> pc) & 1;
  const float ce = ctrl ? cc : 1.0f;
  const float se = ctrl ? sc : 0.0f;
  ar = ce*ar + se*p.y;
  ai = ce*ai - se*p.x;
}

__device__ __forceinline__ unsigned short f2bf(float f) {
  unsigned int u = __float_as_uint(f);
  u = (u + 0x7FFFu + ((u >> 16) & 1u)) >> 16;
  return (unsigned short)u;
}

typedef __attribute__((ext_vector_type(8))) short bf16x8;
typedef __attribute__((ext_vector_type(4))) float f32x4;

// Complex 16x16-tile GEMM body [verified R5/R10]: C = A*B with column-layout
// complex buffers: bufA[k*512 + i*2] = A[i][k], bufB[j*512 + k*2] = B[k][j].
__device__ __forceinline__ void cgemm_tile(const float* __restrict__ bufA,
                                           const float* __restrict__ bufB,
                                           int bi, int bj, int tid,
                                           float& accr, float& acci,
                                           float2* S2 /*32*16*/, float2* S1 /*16*33*/) {
  const int ti = tid & 15;
  const int tj = tid >> 4;
  accr = 0.f; acci = 0.f;
#pragma unroll 1
  for (int kt = 0; kt < 8; ++kt) {
    __syncthreads();
#pragma unroll
    for (int v = 0; v < 2; ++v) {
      const int s = v * 256 + tid;
      const int k = s >> 4, i = s & 15;
      S2[k * 16 + i] = *(const float2*)(bufA + (size_t)(kt*32 + k) * 512 + (bi*16 + i) * 2);
      const int j2 = s >> 5, k2 = s & 31;
      S1[j2 * 33 + k2] = *(const float2*)(bufB + (size_t)(bj*16 + j2) * 512 + (kt*32 + k2) * 2);
    }
    __syncthreads();
#pragma unroll
    for (int kk = 0; kk < 32; ++kk) {
      const float2 a = S2[kk * 16 + ti];
      const float2 b = S1[tj * 33 + kk];
      accr = fmaf(a.x, b.x, accr);  accr = fmaf(-a.y, b.y, accr);
      acci = fmaf(a.x, b.y, acci);  acci = fmaf(a.y, b.x, acci);
    }
  }
}

} // namespace

// ---------------- K1: per-layer unitaries, 4 waves per state ----------------
// block = (layer l, basis s0); thread s = tid holds U_l[s][s0] at the end.
// Writes Uq[(l*256+s0)*512 + s*2] = (re, im) — coalesced float2 stores.
__global__ __launch_bounds__(256) void build_quarter4w(const float* __restrict__ qw,
                                                       float* __restrict__ Uq) {
  __shared__ float4 sM[24];
  __shared__ float2 xbuf[256];
  const int tid = threadIdx.x;
  const int l   = blockIdx.x >> 8;
  const int s0  = blockIdx.x & 255;
  const int s   = tid;

  if (tid < 24) {
    const int j = tid >> 3;
    const int q = tid & 7;
    float a, bb;
    if (j == 0) {        // M0 = RY(qw[l][q]) * RZ(qw[l-1][124+q])
      a  = qw[l * NW_L + q];
      bb = (l > 0) ? qw[(l - 1) * NW_L + 124 + q] : 0.f;
    } else if (j == 1) { // M1 = RX(44+q) * RY(36+q)
      a  = qw[l * NW_L + 44 + q];
      bb = qw[l * NW_L + 36 + q];
    } else {             // M2 = RZ(88+q) * RX(80+q); RZ dropped at l=3
      a  = (l < 3) ? qw[l * NW_L + 88 + q] : 0.f;
      bb = qw[l * NW_L + 80 + q];
    }
    float sa, ca, sb, cb;
    __sincosf(0.5f * a,  &sa, &ca);
    __sincosf(0.5f * bb, &sb, &cb);
    float4 m;
    if (j == 0)      m = make_float4(ca*cb, -ca*sb, -sa*cb, -sa*sb); // RY*RZ
    else if (j == 1) m = make_float4(ca*cb, -sa*sb, -ca*sb, -sa*cb); // RX*RY
    else             m = make_float4(ca*cb, -sa*cb, -sb*sa, -sb*ca); // RZ*RX
    sM[tid] = m;
  }

  float ar = (s == s0) ? 1.f : 0.f;
  float ai = 0.f;
  const float dzr = D_CRZ.v[2*s];
  const float dzi = D_CRZ.v[2*s+1];
  __syncthreads();

  // one layer: M0, CRY, M1, CRX, M2, (CRZ diag if l<3)
#pragma unroll
  for (int q = 0; q < 8; ++q) {
    float4 m = sM[q];
    if (q == 0)      gen_xw(ar, ai, s, 7, m.x, m.y, m.z, m.w, xbuf);
    else if (q == 1) gen_xw(ar, ai, s, 6, m.x, m.y, m.z, m.w, xbuf);
    else             gen_lane(ar, ai, s, 7 - q, m.x, m.y, m.z, m.w);
  }
#pragma unroll
  for (int i = 0; i < 28; ++i) {
    const int pc = 7 - PC[i], pt = 7 - PT[i];
    const float cc = T_CRY.c[i], sc = T_CRY.s[i];
    if (pt == 6) cry_xw(ar, ai, s, pc, pt, cc, sc, xbuf);
    else         cry_lane(ar, ai, s, pc, pt, cc, sc);
  }
#pragma unroll
  for (int q = 0; q < 8; ++q) {
    float4 m = sM[8 + q];
    if (q == 0)      gen_xw(ar, ai, s, 7, m.x, m.y, m.z, m.w, xbuf);
    else if (q == 1) gen_xw(ar, ai, s, 6, m.x, m.y, m.z, m.w, xbuf);
    else             gen_lane(ar, ai, s, 7 - q, m.x, m.y, m.z, m.w);
  }
#pragma unroll
  for (int i = 0; i < 28; ++i) {
    const int pc = 7 - PC[i], pt = 7 - PT[i];
    const float cc = T_CRX.c[i], sc = T_CRX.s[i];
    if (pt == 6) crx_xw(ar, ai, s, pc, pt, cc, sc, xbuf);
    else         crx_lane(ar, ai, s, pc, pt, cc, sc);
  }
#pragma unroll
  for (int q = 0; q < 8; ++q) {
    float4 m = sM[16 + q];
    if (q == 0)      gen_xw(ar, ai, s, 7, m.x, m.y, m.z, m.w, xbuf);
    else if (q == 1) gen_xw(ar, ai, s, 6, m.x, m.y, m.z, m.w, xbuf);
    else             gen_lane(ar, ai, s, 7 - q, m.x, m.y, m.z, m.w);
  }
  if (l < 3) {
    const float mr = ar, mi = ai;
    ar = mr*dzr - mi*dzi;
    ai = mr*dzi + mi*dzr;
  }

  ((float2*)(Uq + (size_t)(l * 256 + s0) * 512))[s] = make_float2(ar, ai);
}

// ---------------- K2: T1=U1*U0 -> U1bf, T2=U3*U2 -> W2bf [R10 verbatim] ----------------
__global__ __launch_bounds__(256) void combine_emit(const float* __restrict__ Uq,
                                                    unsigned short* __restrict__ U1bf,
                                                    unsigned short* __restrict__ W2bf) {
  __shared__ float2 S2[32 * 16];
  __shared__ float2 S1[16 * 33];
  __shared__ float Tre[16][17];
  __shared__ float Tim[16][17];
  const int tid = threadIdx.x;
  const int p   = blockIdx.x >> 8;       // 0: T1, 1: T2
  const int rem = blockIdx.x & 255;
  const int bi  = rem & 15;
  const int bj  = rem >> 4;
  const float* bufA = Uq + (size_t)(2*p + 1) * 256 * 512;
  const float* bufB = Uq + (size_t)(2*p) * 256 * 512;

  float accr, acci;
  cgemm_tile(bufA, bufB, bi, bj, tid, accr, acci, S2, S1);

  Tre[tid & 15][tid >> 4] = accr;
  Tim[tid & 15][tid >> 4] = acci;
  __syncthreads();

  const int part = tid >> 6;
  const int rr   = (tid & 63) >> 2;
  const int cg   = tid & 3;
  unsigned short pk[4];
  if (p == 0) {
    if (part < 2) {   // part 0: Re rows, part 1: Im rows
#pragma unroll
      for (int k = 0; k < 4; ++k)
        pk[k] = f2bf(part ? Tim[rr][cg*4 + k] : Tre[rr][cg*4 + k]);
      const int row = bi * 16 + rr + part * 256;
      *(uint2*)(U1bf + (size_t)row * 256 + bj * 16 + cg * 4) = *(const uint2*)pk;
    }
  } else {
    // W2 = [[Re,-Im],[Im,Re]]
#pragma unroll
    for (int k = 0; k < 4; ++k) {
      const float v = (part == 0 || part == 3) ? Tre[rr][cg*4 + k]
                    : (part == 1 ? -Tim[rr][cg*4 + k] : Tim[rr][cg*4 + k]);
      pk[k] = f2bf(v);
    }
    const int row = bi * 16 + rr + ((part >= 2) ? 256 : 0);
    const int col = bj * 16 + cg * 4 + ((part & 1) ? 256 : 0);
    *(uint2*)(W2bf + (size_t)row * 512 + col) = *(const uint2*)pk;
  }
}

// ---------------- K3: y = T1 x ; amps = W2 y ; fused epilogue [R8/R13 verbatim] ----------------
__global__ __launch_bounds__(1024) void eval_chain(const float* __restrict__ x,
                                                   const unsigned short* __restrict__ U1bf,
                                                   const unsigned short* __restrict__ W2bf,
                                                   const float* __restrict__ fcw,
                                                   const float* __restrict__ fcb,
                                                   float* __restrict__ out) {
  __shared__ unsigned short Xs[16 * 264];   // [col][k 0..255] bf16
  __shared__ unsigned short Ys[16 * 520];   // [col][k 0..511] bf16
  __shared__ float Zp[16][16][9];
  __shared__ float Zf[16][9];
  const int tid  = threadIdx.x;
  const int lane = tid & 63;
  const int w    = tid >> 6;                // 0..15
  const int colbase = blockIdx.x * 16;

  {
    const int k  = tid >> 2;
    const int c4 = (tid & 3) * 4;
    const float4 v = *(const float4*)(x + (size_t)k * NSAMP + colbase + c4);
    Xs[(c4 + 0) * 264 + k] = f2bf(v.x);
    Xs[(c4 + 1) * 264 + k] = f2bf(v.y);
    Xs[(c4 + 2) * 264 + k] = f2bf(v.z);
    Xs[(c4 + 3) * 264 + k] = f2bf(v.w);
  }
  __syncthreads();

  const int quad = lane >> 4;
  const int n    = lane & 15;
  const int rowb = w * 32;

  // ---- stage 1: y = T1 * x (512 x 16, K=256) ----
  {
    f32x4 a1[2];
    a1[0] = (f32x4){0.f, 0.f, 0.f, 0.f};
    a1[1] = (f32x4){0.f, 0.f, 0.f, 0.f};
#pragma unroll
    for (int kt = 0; kt < 8; ++kt) {
      const bf16x8 bfrag = *(const bf16x8*)&Xs[n * 264 + kt * 32 + quad * 8];
#pragma unroll
      for (int rt = 0; rt < 2; ++rt) {
        const int row = rowb + rt * 16 + n;
        const bf16x8 afrag = *(const bf16x8*)(U1bf + (size_t)row * 256 + kt * 32 + quad * 8);
        a1[rt] = __builtin_amdgcn_mfma_f32_16x16x32_bf16(afrag, bfrag, a1[rt], 0, 0, 0);
      }
    }
#pragma unroll
    for (int rt = 0; rt < 2; ++rt) {
      unsigned short p4[4];
#pragma unroll
      for (int reg = 0; reg < 4; ++reg) p4[reg] = f2bf(a1[rt][reg]);
      *(uint2*)&Ys[n * 520 + rowb + rt * 16 + quad * 4] = *(const uint2*)p4;
    }
  }
  __syncthreads();

  // ---- stage 2: amps_stacked = W2 * y (512 x 16, K=512) ----
  f32x4 acc[2];
  acc[0] = (f32x4){0.f, 0.f, 0.f, 0.f};
  acc[1] = (f32x4){0.f, 0.f, 0.f, 0.f};
#pragma unroll
  for (int kt = 0; kt < 16; ++kt) {
    const bf16x8 bfrag = *(const bf16x8*)&Ys[n * 520 + kt * 32 + quad * 8];
#pragma unroll
    for (int rt = 0; rt < 2; ++rt) {
      const int row = rowb + rt * 16 + n;
      const bf16x8 afrag = *(const bf16x8*)(W2bf + (size_t)row * 512 + kt * 32 + quad * 8);
      acc[rt] = __builtin_amdgcn_mfma_f32_16x16x32_bf16(afrag, bfrag, acc[rt], 0, 0, 0);
    }
  }

  // epilogue: amp at (row = w*32 + rt*16 + quad*4 + reg, col = n);
  // s = (w&7)*32 + rt*16 + quad*4 + reg  (w<8: Re, w>=8: Im)
  float za[9];
#pragma unroll
  for (int i = 0; i < 9; ++i) za[i] = 0.f;
  const float m4 = (lane & 32) ? -1.f : 1.f;
  const float m5 = (lane & 16) ? -1.f : 1.f;
#pragma unroll
  for (int rt = 0; rt < 2; ++rt) {
#pragma unroll
    for (int reg = 0; reg < 4; ++reg) {
      const float v = acc[rt][reg];
      const float p = v * v;
      za[0] += p;
      za[1] += (w & 4)   ? -p : p;
      za[2] += (w & 2)   ? -p : p;
      za[3] += (w & 1)   ? -p : p;
      za[4] += rt        ? -p : p;
      za[5] = fmaf(m4, p, za[5]);
      za[6] = fmaf(m5, p, za[6]);
      za[7] += (reg & 2) ? -p : p;
      za[8] += (reg & 1) ? -p : p;
    }
  }
#pragma unroll
  for (int off = 16; off <= 32; off <<= 1) {
#pragma unroll
    for (int i = 0; i < 9; ++i) za[i] += __shfl_xor(za[i], off, 64);
  }
  if (lane < 16) {
#pragma unroll
    for (int i = 0; i < 9; ++i) Zp[w][lane][i] = za[i];
  }
  __syncthreads();

  if (tid < 144) {
    const int col = tid / 9, q = tid - col * 9;
    float z = 0.f;
#pragma unroll
    for (int ww = 0; ww < 16; ++ww) z += Zp[ww][col][q];
    Zf[col][q] = z;
  }
  __syncthreads();

  if (tid < 112) {
    const int col = tid / 7, oo = tid - col * 7;
    const float inv = 1.f / Zf[col][0];
    float v = fcb[oo];
#pragma unroll
    for (int q = 0; q < 8; ++q)
      v = fmaf(fcw[oo * 8 + q], Zf[col][1 + q] * inv, v);
    out[(size_t)(colbase + col) * 7 + oo] = v;
  }
}

extern "C" void kernel_launch(void* const* d_in, const int* in_sizes, int n_in,
                              void* d_out, int out_size, void* d_ws, size_t ws_size,
                              hipStream_t stream) {
  const float* x   = (const float*)d_in[0];   // [256, 4096]
  const float* qw  = (const float*)d_in[1];   // [4, 132]
  const float* fcw = (const float*)d_in[2];   // [7, 8]
  const float* fcb = (const float*)d_in[3];   // [7]
  float* out = (float*)d_out;                 // [4096, 7]

  float* Uq = (float*)d_ws;                                  // 4 x 256x256 cfp32 (2 MB)
  unsigned short* U1bf = (unsigned short*)(Uq + (size_t)4 * 256 * 512);  // 256 KB
  unsigned short* W2bf = U1bf + (size_t)512 * 256;                        // 512 KB

  hipLaunchKernelGGL(build_quarter4w, dim3(1024), dim3(256),  0, stream, qw, Uq);
  hipLaunchKernelGGL(combine_emit,    dim3(512),  dim3(256),  0, stream, Uq, U1bf, W2bf);
  hipLaunchKernelGGL(eval_chain,      dim3(256),  dim3(1024), 0, stream,
                     x, U1bf, W2bf, fcw, fcb, out);
}

// Round 15
// 95.714 us; speedup vs baseline: 1.1037x; 1.1037x over previous
//
#include <hip/hip_runtime.h>
#include <math.h>

// QuGCN pipeline v14 (R12 structure; build's cross-wave gates fused):
//   K1 build_half4w_f : 512 blk x 256 thr (2 waves/SIMD). Block (h,s0)
//                       simulates basis e_{s0} through half h, 1 amp/thread.
//                       Gates on bits 7,6 fused into 3 complex 4x4 matrices
//                       per layer (commutation-exact) -> 3 LDS exchanges +
//                       3 barriers per layer (was 8 / 16). Lane gates
//                       verbatim R12.
//   K2 combine_u      : U = U2*U1 complex GEMM (fp32), emits bf16 [re;im].
//                       [R7/R12 verbatim]
//   K3 eval3          : amps = U*x via mfma 16x16x32 bf16, 16 waves/block,
//                       fused |amp|^2 -> <Z_q> -> norm -> head. [R7/R12 verbatim]

namespace {

constexpr int NSAMP = 4096;
constexpr int NW_L  = 132;

// ---------- compile-time trig ----------
constexpr double PI_D   = 3.14159265358979323846264338327950288;
constexpr double TWO_PI = 6.28318530717958647692528676655900577;

constexpr double red_pm_pi(double x) {
  double k = x / TWO_PI;
  long long ki = (long long)k;
  double r = x - (double)ki * TWO_PI;
  if (r > PI_D)  r -= TWO_PI;
  if (r < -PI_D) r += TWO_PI;
  return r;
}
constexpr double csin(double x) {
  double r = red_pm_pi(x), r2 = r * r, term = r, sum = r;
  for (int n = 1; n <= 13; ++n) { term *= -r2 / (double)((2*n)*(2*n+1)); sum += term; }
  return sum;
}
constexpr double ccos(double x) {
  double r = red_pm_pi(x), r2 = r * r, term = 1.0, sum = 1.0;
  for (int n = 1; n <= 13; ++n) { term *= -r2 / (double)((2*n-1)*(2*n)); sum += term; }
  return sum;
}

constexpr int PC[28] = {0,1,2,3,4,5,6, 0,1,2,3,4,5, 0,1,2,3,4, 0,1,2,3, 0,1,2, 0,1, 0};
constexpr int PT[28] = {1,2,3,4,5,6,7, 2,3,4,5,6,7, 3,4,5,6,7, 4,5,6,7, 5,6,7, 6,7, 7};

struct Tbl28 { float c[28]; float s[28]; };
constexpr Tbl28 mk_tbl(int base) {
  Tbl28 t{};
  for (int i = 0; i < 28; ++i) {
    double a = 0.5 * (double)(base + i);
    t.c[i] = (float)ccos(a);
    t.s[i] = (float)csin(a);
  }
  return t;
}
constexpr Tbl28 T_CRY = mk_tbl(8);
constexpr Tbl28 T_CRX = mk_tbl(52);

struct DTbl { float v[512]; };
constexpr DTbl mk_dcrz() {
  DTbl t{};
  for (int s = 0; s < 256; ++s) {
    double psi = 0.0;
    for (int i = 0; i < 28; ++i) {
      const int pc = 7 - PC[i], pt = 7 - PT[i];
      if ((s >> pc) & 1) {
        const double half = 0.5 * (double)(96 + i);
        psi += ((s >> pt) & 1) ? half : -half;
      }
    }
    t.v[2*s]   = (float)ccos(psi);
    t.v[2*s+1] = (float)csin(psi);
  }
  return t;
}
__device__ constexpr DTbl D_CRZ = mk_dcrz();

// ---------- single-amp cross-lane xor on lane bit p (0..5) [verified R12] ----------
__device__ __forceinline__ float shx1(float v, int p) {
  if (p == 0) {
    int r = __builtin_amdgcn_update_dpp((int)__float_as_uint(v), (int)__float_as_uint(v),
                                        0xB1, 0xF, 0xF, true);
    return __uint_as_float((unsigned)r);
  }
  if (p == 1) {
    int r = __builtin_amdgcn_update_dpp((int)__float_as_uint(v), (int)__float_as_uint(v),
                                        0x4E, 0xF, 0xF, true);
    return __uint_as_float((unsigned)r);
  }
  if (p == 2) return __uint_as_float((unsigned)__builtin_amdgcn_ds_swizzle(
                      (int)__float_as_uint(v), 0x101F));   // xor 4
  if (p == 3) return __uint_as_float((unsigned)__builtin_amdgcn_ds_swizzle(
                      (int)__float_as_uint(v), 0x201F));   // xor 8
  if (p == 4) return __uint_as_float((unsigned)__builtin_amdgcn_ds_swizzle(
                      (int)__float_as_uint(v), 0x401F));   // xor 16
  return __shfl_xor(v, 32, 64);
}

// ---------- single-amp lane-gate appliers [verified R12] ----------
__device__ __forceinline__ void gen_lane(float& ar, float& ai, int s, int p,
                                         float m00r, float m00i, float m01r, float m01i) {
  const int b = (s >> p) & 1;
  const float dr = m00r;
  const float di = b ? -m00i : m00i;
  const float g  = b ? -m01r : m01r;
  const float hh = m01i;
  const float pr = shx1(ar, p);
  const float pi = shx1(ai, p);
  const float mr = ar, mi = ai;
  ar = dr*mr - di*mi + g*pr - hh*pi;
  ai = dr*mi + di*mr + g*pi + hh*pr;
}
__device__ __forceinline__ void cry_lane(float& ar, float& ai, int s, int pc, int pt,
                                         float cc, float sc) {
  const int ctrl = (s >> pc) & 1;
  const float ce = ctrl ? cc : 1.0f;
  float se = ((s >> pt) & 1) ? sc : -sc;
  se = ctrl ? se : 0.0f;
  const float pr = shx1(ar, pt);
  const float pi = shx1(ai, pt);
  ar = ce*ar + se*pr;
  ai = ce*ai + se*pi;
}
__device__ __forceinline__ void crx_lane(float& ar, float& ai, int s, int pc, int pt,
                                         float cc, float sc) {
  const int ctrl = (s >> pc) & 1;
  const float ce = ctrl ? cc : 1.0f;
  const float se = ctrl ? sc : 0.0f;
  const float pr = shx1(ar, pt);
  const float pi = shx1(ai, pt);
  ar = ce*ar + se*pi;
  ai = ce*ai - se*pr;
}

// 2x2 complex entry from fused float4 (m00=(x,y), m01=(z,w), m10=-conj(m01), m11=conj(m00))
__device__ __forceinline__ float2 mat2(float4 m, int r, int c) {
  if (r == 0) return (c == 0) ? make_float2(m.x, m.y) : make_float2(m.z, m.w);
  return (c == 0) ? make_float2(-m.z, m.w) : make_float2(m.x, -m.y);
}

__device__ __forceinline__ unsigned short f2bf(float f) {
  unsigned int u = __float_as_uint(f);
  u = (u + 0x7FFFu + ((u >> 16) & 1u)) >> 16;
  return (unsigned short)u;
}

typedef __attribute__((ext_vector_type(8))) short bf16x8;
typedef __attribute__((ext_vector_type(4))) float f32x4;

} // namespace

// ---------------- K1: half-circuit unitaries, 4 waves/state, fused (7,6)-gates ----------------
// block = (half h, basis s0); thread s = tid holds U_h[s][s0] at the end.
// Per layer: G0 (=CRY01*(M0q0 x M0q1)), M0 lanes q2-7, CRY i=1..27,
//            G1 (=CRX01*(M1q0 x M1q1)), M1 lanes, CRX i=1..27,
//            G2 (=M2q0 x M2q1), M2 lanes, Dcrz (l<3).
// All reorderings are exact (disjoint-bit commutation).
__global__ __launch_bounds__(256) void build_half4w_f(const float* __restrict__ qw,
                                                      float* __restrict__ U1c,
                                                      float* __restrict__ U2c) {
  __shared__ float4 sM[48];
  __shared__ float2 sG[2][3][16];      // [layer-in-half][matrix][v*4+u]
  __shared__ float2 xb[2][256];        // double-buffered exchange
  const int tid = threadIdx.x;
  const int h   = blockIdx.x >> 8;
  const int s0  = blockIdx.x & 255;
  const int s   = tid;

  // phase 1: fused per-wire 2x2 matrices (verified R2-R12)
  if (tid < 48) {
    const int lp  = tid / 24;
    const int rem = tid - lp * 24;
    const int j   = rem >> 3;
    const int q   = rem & 7;
    const int l   = 2 * h + lp;
    float a, bb;
    if (j == 0) {        // M0 = RY(qw[l][q]) * RZ(qw[l-1][124+q])
      a  = qw[l * NW_L + q];
      bb = (l > 0) ? qw[(l - 1) * NW_L + 124 + q] : 0.f;
    } else if (j == 1) { // M1 = RX(44+q) * RY(36+q)
      a  = qw[l * NW_L + 44 + q];
      bb = qw[l * NW_L + 36 + q];
    } else {             // M2 = RZ(88+q) * RX(80+q); RZ dropped at l=3
      a  = (l < 3) ? qw[l * NW_L + 88 + q] : 0.f;
      bb = qw[l * NW_L + 80 + q];
    }
    float sa, ca, sb, cb;
    __sincosf(0.5f * a,  &sa, &ca);
    __sincosf(0.5f * bb, &sb, &cb);
    float4 m;
    if (j == 0)      m = make_float4(ca*cb, -ca*sb, -sa*cb, -sa*sb); // RY*RZ
    else if (j == 1) m = make_float4(ca*cb, -sa*sb, -ca*sb, -sa*cb); // RX*RY
    else             m = make_float4(ca*cb, -sa*cb, -sb*sa, -sb*ca); // RZ*RX
    sM[tid] = m;
  }
  __syncthreads();

  // phase 2: fused 4x4 matrices on bits (7,6). v=2a+b rows, u=2a'+b' cols.
  // G[v][u] = A[a][a'] * Brow, Brow = B[b][b'] (a==0 or G2) else (R*B)[b][b'].
  if (tid < 96) {
    const int lp = tid / 48;
    const int rm = tid - lp * 48;
    const int mi = rm >> 4;            // 0: M0+CRY01, 1: M1+CRX01, 2: M2
    const int e  = rm & 15;
    const int v  = e >> 2, u = e & 3;
    const int a  = v >> 1, b = v & 1, ap = u >> 1, bp = u & 1;
    const float4 A4 = sM[lp * 24 + mi * 8 + 0];   // q0 (bit 7)
    const float4 B4 = sM[lp * 24 + mi * 8 + 1];   // q1 (bit 6)
    const float2 A = mat2(A4, a, ap);
    float2 Bv;
    if (mi == 2 || a == 0) {
      Bv = mat2(B4, b, bp);
    } else {
      const float2 B0 = mat2(B4, 0, bp);
      const float2 B1 = mat2(B4, 1, bp);
      if (mi == 0) {   // CRY: R = [[c,-s],[s,c]] (real)
        const float c = T_CRY.c[0], sg = T_CRY.s[0];
        Bv = (b == 0) ? make_float2(c*B0.x - sg*B1.x, c*B0.y - sg*B1.y)
                      : make_float2(sg*B0.x + c*B1.x, sg*B0.y + c*B1.y);
      } else {         // CRX: R = [[c,-is],[-is,c]]; (-is)*(x+iy) = (s*y, -s*x)
        const float c = T_CRX.c[0], sg = T_CRX.s[0];
        Bv = (b == 0) ? make_float2(c*B0.x + sg*B1.y, c*B0.y - sg*B1.x)
                      : make_float2(sg*B0.y + c*B1.x, -sg*B0.x + c*B1.y);
      }
    }
    sG[lp][mi][e] = make_float2(A.x*Bv.x - A.y*Bv.y, A.x*Bv.y + A.y*Bv.x);
  }

  float ar = (s == s0) ? 1.f : 0.f;
  float ai = 0.f;
  const float dzr = D_CRZ.v[2*s];
  const float dzi = D_CRZ.v[2*s+1];
  const int v    = s >> 6;
  const int slow = s & 63;
  __syncthreads();

  int pb = 0;  // exchange-buffer toggle (1 barrier per fused gate)
#pragma unroll 1
  for (int lp = 0; lp < 2; ++lp) {
    const int base = lp * 24;
#pragma unroll 1
    for (int mi = 0; mi < 3; ++mi) {
      // fused 4x4 on bits (7,6)
      {
        float2* buf = xb[pb];
        buf[s] = make_float2(ar, ai);
        __syncthreads();
        float nr = 0.f, ni = 0.f;
#pragma unroll
        for (int u = 0; u < 4; ++u) {
          const float2 g = sG[lp][mi][v * 4 + u];
          const float2 p = buf[slow + 64 * u];
          nr += g.x*p.x - g.y*p.y;
          ni += g.x*p.y + g.y*p.x;
        }
        ar = nr; ai = ni;
        pb ^= 1;
      }
      // lane gates of this M block (q = 2..7)
#pragma unroll
      for (int q = 2; q < 8; ++q) {
        float4 m = sM[base + mi * 8 + q];
        gen_lane(ar, ai, s, 7 - q, m.x, m.y, m.z, m.w);
      }
      // CR block (i = 1..27, all lane-target) after M0/M1 blocks
      if (mi == 0) {
#pragma unroll
        for (int i = 1; i < 28; ++i) {
          const int pc = 7 - PC[i], pt = 7 - PT[i];
          cry_lane(ar, ai, s, pc, pt, T_CRY.c[i], T_CRY.s[i]);
        }
      } else if (mi == 1) {
#pragma unroll
        for (int i = 1; i < 28; ++i) {
          const int pc = 7 - PC[i], pt = 7 - PT[i];
          crx_lane(ar, ai, s, pc, pt, T_CRX.c[i], T_CRX.s[i]);
        }
      }
    }
    // CRZ diagonal (dropped at l == 3)
    if (2 * h + lp < 3) {
      const float mr = ar, mi2 = ai;
      ar = mr*dzr - mi2*dzi;
      ai = mr*dzi + mi2*dzr;
    }
  }

  // emit: Uc[s0*512 + s*2] = (re, im) — coalesced float2 stores
  float* Uc = h ? U2c : U1c;
  ((float2*)(Uc + (size_t)s0 * 512))[s] = make_float2(ar, ai);
}

// ---------------- K2: U = U2 * U1 (complex), emit bf16 (R12 verbatim) ----------------
__global__ __launch_bounds__(256) void combine_u(const float* __restrict__ U1c,
                                                 const float* __restrict__ U2c,
                                                 unsigned short* __restrict__ Ubf) {
  __shared__ float2 S2[32 * 16];   // [kk][i]
  __shared__ float2 S1[16 * 33];   // [j][kk] padded
  const int tid = threadIdx.x;
  const int ti  = tid & 15;
  const int tj  = tid >> 4;
  const int bi  = blockIdx.x & 15;
  const int bj  = blockIdx.x >> 4;

  float accr = 0.f, acci = 0.f;
#pragma unroll 1
  for (int kt = 0; kt < 8; ++kt) {
    __syncthreads();
#pragma unroll
    for (int v = 0; v < 2; ++v) {
      const int s = v * 256 + tid;
      const int k  = s >> 4, i = s & 15;
      S2[k * 16 + i] = *(const float2*)(U2c + (size_t)(kt*32 + k) * 512 + (bi*16 + i) * 2);
      const int j2 = s >> 5, k2 = s & 31;
      S1[j2 * 33 + k2] = *(const float2*)(U1c + (size_t)(bj*16 + j2) * 512 + (kt*32 + k2) * 2);
    }
    __syncthreads();
#pragma unroll
    for (int kk = 0; kk < 32; ++kk) {
      const float2 a = S2[kk * 16 + ti];
      const float2 b = S1[tj * 33 + kk];
      accr = fmaf(a.x, b.x, accr);  accr = fmaf(-a.y, b.y, accr);
      acci = fmaf(a.x, b.y, acci);  acci = fmaf(a.y, b.x, acci);
    }
  }
  const int i = bi * 16 + ti, j = bj * 16 + tj;
  Ubf[(size_t)i * 256 + j]         = f2bf(accr);
  Ubf[(size_t)(i + 256) * 256 + j] = f2bf(acci);
}

// ---------------- K3: eval3 — 16 waves/block, 32 rows/wave (R12 verbatim) ----------------
__global__ __launch_bounds__(1024) void eval3(const float* __restrict__ x,
                                              const unsigned short* __restrict__ Ubf,
                                              const float* __restrict__ fcw,
                                              const float* __restrict__ fcb,
                                              float* __restrict__ out) {
  __shared__ unsigned short Xs[16 * 264];   // [col][k] bf16, padded
  __shared__ float Zp[16][16][9];           // [wave][col][9]
  __shared__ float Zf[16][9];
  const int tid  = threadIdx.x;
  const int lane = tid & 63;
  const int w    = tid >> 6;                // 0..15
  const int colbase = blockIdx.x * 16;

  {
    const int k  = tid >> 2;
    const int c4 = (tid & 3) * 4;
    const float4 v = *(const float4*)(x + (size_t)k * NSAMP + colbase + c4);
    Xs[(c4 + 0) * 264 + k] = f2bf(v.x);
    Xs[(c4 + 1) * 264 + k] = f2bf(v.y);
    Xs[(c4 + 2) * 264 + k] = f2bf(v.z);
    Xs[(c4 + 3) * 264 + k] = f2bf(v.w);
  }
  __syncthreads();

  const int quad = lane >> 4;
  const int n    = lane & 15;
  const int rowb = w * 32;

  f32x4 acc[2];
  acc[0] = (f32x4){0.f, 0.f, 0.f, 0.f};
  acc[1] = (f32x4){0.f, 0.f, 0.f, 0.f};

#pragma unroll
  for (int kt = 0; kt < 8; ++kt) {
    const bf16x8 bfrag = *(const bf16x8*)&Xs[n * 264 + kt * 32 + quad * 8];
#pragma unroll
    for (int rt = 0; rt < 2; ++rt) {
      const int row = rowb + rt * 16 + n;
      const bf16x8 afrag = *(const bf16x8*)(Ubf + (size_t)row * 256 + kt * 32 + quad * 8);
      acc[rt] = __builtin_amdgcn_mfma_f32_16x16x32_bf16(afrag, bfrag, acc[rt], 0, 0, 0);
    }
  }

  float za[9];
#pragma unroll
  for (int i = 0; i < 9; ++i) za[i] = 0.f;
  const float m4 = (lane & 32) ? -1.f : 1.f;   // s bit3 = quad bit1
  const float m5 = (lane & 16) ? -1.f : 1.f;   // s bit2 = quad bit0
#pragma unroll
  for (int rt = 0; rt < 2; ++rt) {
#pragma unroll
    for (int reg = 0; reg < 4; ++reg) {
      const float v = acc[rt][reg];
      const float p = v * v;
      za[0] += p;
      za[1] += (w & 4)   ? -p : p;   // q0: s bit7
      za[2] += (w & 2)   ? -p : p;   // q1: s bit6
      za[3] += (w & 1)   ? -p : p;   // q2: s bit5
      za[4] += rt        ? -p : p;   // q3: s bit4
      za[5] = fmaf(m4, p, za[5]);    // q4
      za[6] = fmaf(m5, p, za[6]);    // q5
      za[7] += (reg & 2) ? -p : p;   // q6: s bit1
      za[8] += (reg & 1) ? -p : p;   // q7: s bit0
    }
  }
#pragma unroll
  for (int off = 16; off <= 32; off <<= 1) {
#pragma unroll
    for (int i = 0; i < 9; ++i) za[i] += __shfl_xor(za[i], off, 64);
  }
  if (lane < 16) {
#pragma unroll
    for (int i = 0; i < 9; ++i) Zp[w][lane][i] = za[i];
  }
  __syncthreads();

  if (tid < 144) {
    const int col = tid / 9, q = tid - col * 9;
    float z = 0.f;
#pragma unroll
    for (int ww = 0; ww < 16; ++ww) z += Zp[ww][col][q];
    Zf[col][q] = z;
  }
  __syncthreads();

  if (tid < 112) {
    const int col = tid / 7, oo = tid - col * 7;
    const float inv = 1.f / Zf[col][0];
    float v = fcb[oo];
#pragma unroll
    for (int q = 0; q < 8; ++q)
      v = fmaf(fcw[oo * 8 + q], Zf[col][1 + q] * inv, v);
    out[(size_t)(colbase + col) * 7 + oo] = v;
  }
}

extern "C" void kernel_launch(void* const* d_in, const int* in_sizes, int n_in,
                              void* d_out, int out_size, void* d_ws, size_t ws_size,
                              hipStream_t stream) {
  const float* x   = (const float*)d_in[0];   // [256, 4096]
  const float* qw  = (const float*)d_in[1];   // [4, 132]
  const float* fcw = (const float*)d_in[2];   // [7, 8]
  const float* fcb = (const float*)d_in[3];   // [7]
  float* out = (float*)d_out;                 // [4096, 7]

  float* U1c = (float*)d_ws;                      // 256x256 complex fp32 (512 KB)
  float* U2c = U1c + 256 * 512;                   // 512 KB
  unsigned short* Ubf = (unsigned short*)(U2c + 256 * 512);  // 512x256 bf16 (256 KB)

  hipLaunchKernelGGL(build_half4w_f, dim3(512), dim3(256),  0, stream, qw, U1c, U2c);
  hipLaunchKernelGGL(combine_u,      dim3(256), dim3(256),  0, stream, U1c, U2c, Ubf);
  hipLaunchKernelGGL(eval3,          dim3(256), dim3(1024), 0, stream, x, Ubf, fcw, fcb, out);
}

// Round 16
// 88.946 us; speedup vs baseline: 1.1877x; 1.0761x over previous
//
#include <hip/hip_runtime.h>
#include <math.h>

// QuGCN pipeline v15 = R12 (best, 89.3 us) + double-buffered cross-wave
// exchange in the build (32 -> 16 barriers; strictly subtractive change).
//   K1 build_half4w : 512 blk x 256 thr (2048 waves = 2/SIMD). Block (h,s0)
//                     simulates basis e_{s0} through half h (U = U2*U1, exact
//                     split), 1 complex amp per thread (amp = tid). Gates on
//                     bits 0..5 = in-wave shuffles (DPP / ds_swizzle / shfl);
//                     bits 6,7 = LDS exchange, double-buffered: ONE barrier
//                     per exchange (reuse of a buffer is ordered by the next
//                     exchange's barrier).
//   K2 combine_u    : U = U2*U1 complex GEMM (fp32), emits bf16 [re;im]. [R12]
//   K3 eval3        : amps = U*x via mfma_f32_16x16x32_bf16, 16 waves/block,
//                     fused |amp|^2 -> <Z_q> -> norm -> head. [R12]

namespace {

constexpr int NSAMP = 4096;
constexpr int NW_L  = 132;

// ---------- compile-time trig ----------
constexpr double PI_D   = 3.14159265358979323846264338327950288;
constexpr double TWO_PI = 6.28318530717958647692528676655900577;

constexpr double red_pm_pi(double x) {
  double k = x / TWO_PI;
  long long ki = (long long)k;
  double r = x - (double)ki * TWO_PI;
  if (r > PI_D)  r -= TWO_PI;
  if (r < -PI_D) r += TWO_PI;
  return r;
}
constexpr double csin(double x) {
  double r = red_pm_pi(x), r2 = r * r, term = r, sum = r;
  for (int n = 1; n <= 13; ++n) { term *= -r2 / (double)((2*n)*(2*n+1)); sum += term; }
  return sum;
}
constexpr double ccos(double x) {
  double r = red_pm_pi(x), r2 = r * r, term = 1.0, sum = 1.0;
  for (int n = 1; n <= 13; ++n) { term *= -r2 / (double)((2*n-1)*(2*n)); sum += term; }
  return sum;
}

constexpr int PC[28] = {0,1,2,3,4,5,6, 0,1,2,3,4,5, 0,1,2,3,4, 0,1,2,3, 0,1,2, 0,1, 0};
constexpr int PT[28] = {1,2,3,4,5,6,7, 2,3,4,5,6,7, 3,4,5,6,7, 4,5,6,7, 5,6,7, 6,7, 7};

struct Tbl28 { float c[28]; float s[28]; };
constexpr Tbl28 mk_tbl(int base) {
  Tbl28 t{};
  for (int i = 0; i < 28; ++i) {
    double a = 0.5 * (double)(base + i);
    t.c[i] = (float)ccos(a);
    t.s[i] = (float)csin(a);
  }
  return t;
}
constexpr Tbl28 T_CRY = mk_tbl(8);
constexpr Tbl28 T_CRX = mk_tbl(52);

struct DTbl { float v[512]; };
constexpr DTbl mk_dcrz() {
  DTbl t{};
  for (int s = 0; s < 256; ++s) {
    double psi = 0.0;
    for (int i = 0; i < 28; ++i) {
      const int pc = 7 - PC[i], pt = 7 - PT[i];
      if ((s >> pc) & 1) {
        const double half = 0.5 * (double)(96 + i);
        psi += ((s >> pt) & 1) ? half : -half;
      }
    }
    t.v[2*s]   = (float)ccos(psi);
    t.v[2*s+1] = (float)csin(psi);
  }
  return t;
}
__device__ constexpr DTbl D_CRZ = mk_dcrz();

// ---------- single-amp cross-lane xor on lane bit p (0..5) [verified R12] ----------
__device__ __forceinline__ float shx1(float v, int p) {
  if (p == 0) {
    int r = __builtin_amdgcn_update_dpp((int)__float_as_uint(v), (int)__float_as_uint(v),
                                        0xB1, 0xF, 0xF, true);
    return __uint_as_float((unsigned)r);
  }
  if (p == 1) {
    int r = __builtin_amdgcn_update_dpp((int)__float_as_uint(v), (int)__float_as_uint(v),
                                        0x4E, 0xF, 0xF, true);
    return __uint_as_float((unsigned)r);
  }
  if (p == 2) return __uint_as_float((unsigned)__builtin_amdgcn_ds_swizzle(
                      (int)__float_as_uint(v), 0x101F));   // xor 4
  if (p == 3) return __uint_as_float((unsigned)__builtin_amdgcn_ds_swizzle(
                      (int)__float_as_uint(v), 0x201F));   // xor 8
  if (p == 4) return __uint_as_float((unsigned)__builtin_amdgcn_ds_swizzle(
                      (int)__float_as_uint(v), 0x401F));   // xor 16
  return __shfl_xor(v, 32, 64);
}

// ---------- single-amp gate appliers [verified R12; xw variants now take an
// explicit (pre-toggled) buffer and use ONE barrier] ----------
__device__ __forceinline__ void gen_lane(float& ar, float& ai, int s, int p,
                                         float m00r, float m00i, float m01r, float m01i) {
  const int b = (s >> p) & 1;
  const float dr = m00r;
  const float di = b ? -m00i : m00i;
  const float g  = b ? -m01r : m01r;
  const float hh = m01i;
  const float pr = shx1(ar, p);
  const float pi = shx1(ai, p);
  const float mr = ar, mi = ai;
  ar = dr*mr - di*mi + g*pr - hh*pi;
  ai = dr*mi + di*mr + g*pi + hh*pr;
}
__device__ __forceinline__ void gen_xw(float& ar, float& ai, int s, int p,
                                       float m00r, float m00i, float m01r, float m01i,
                                       float2* buf) {
  buf[s] = make_float2(ar, ai);
  __syncthreads();
  const float2 pt = buf[s ^ (1 << p)];
  const int b = (s >> p) & 1;
  const float dr = m00r;
  const float di = b ? -m00i : m00i;
  const float g  = b ? -m01r : m01r;
  const float hh = m01i;
  const float mr = ar, mi = ai;
  ar = dr*mr - di*mi + g*pt.x - hh*pt.y;
  ai = dr*mi + di*mr + g*pt.y + hh*pt.x;
}
__device__ __forceinline__ void cry_lane(float& ar, float& ai, int s, int pc, int pt,
                                         float cc, float sc) {
  const int ctrl = (s >> pc) & 1;
  const float ce = ctrl ? cc : 1.0f;
  float se = ((s >> pt) & 1) ? sc : -sc;
  se = ctrl ? se : 0.0f;
  const float pr = shx1(ar, pt);
  const float pi = shx1(ai, pt);
  ar = ce*ar + se*pr;
  ai = ce*ai + se*pi;
}
__device__ __forceinline__ void cry_xw(float& ar, float& ai, int s, int pc, int pt,
                                       float cc, float sc, float2* buf) {
  buf[s] = make_float2(ar, ai);
  __syncthreads();
  const float2 p = buf[s ^ (1 << pt)];
  const int ctrl = (s >> pc) & 1;
  const float ce = ctrl ? cc : 1.0f;
  float se = ((s >> pt) & 1) ? sc : -sc;
  se = ctrl ? se : 0.0f;
  ar = ce*ar + se*p.x;
  ai = ce*ai + se*p.y;
}
__device__ __forceinline__ void crx_lane(float& ar, float& ai, int s, int pc, int pt,
                                         float cc, float sc) {
  const int ctrl = (s >> pc) & 1;
  const float ce = ctrl ? cc : 1.0f;
  const float se = ctrl ? sc : 0.0f;
  const float pr = shx1(ar, pt);
  const float pi = shx1(ai, pt);
  ar = ce*ar + se*pi;
  ai = ce*ai - se*pr;
}
__device__ __forceinline__ void crx_xw(float& ar, float& ai, int s, int pc, int pt,
                                       float cc, float sc, float2* buf) {
  buf[s] = make_float2(ar, ai);
  __syncthreads();
  const float2 p = buf[s ^ (1 << pt)];
  const int ctrl = (s >> pc) & 1;
  const float ce = ctrl ? cc : 1.0f;
  const float se = ctrl ? sc : 0.0f;
  ar = ce*ar + se*p.y;
  ai = ce*ai - se*p.x;
}

__device__ __forceinline__ unsigned short f2bf(float f) {
  unsigned int u = __float_as_uint(f);
  u = (u + 0x7FFFu + ((u >> 16) & 1u)) >> 16;
  return (unsigned short)u;
}

typedef __attribute__((ext_vector_type(8))) short bf16x8;
typedef __attribute__((ext_vector_type(4))) float f32x4;

} // namespace

// ---------------- K1: build half-circuit unitaries, 4 waves per state ----------------
// block = (half h, basis s0); thread tid holds amp s = tid.
// Double-buffered exchanges: buffer reuse is ordered by the NEXT exchange's
// barrier (each thread's reads of buffer A precede its store+barrier of
// buffer B, which precede any re-store of A).
__global__ __launch_bounds__(256) void build_half4w(const float* __restrict__ qw,
                                                    float* __restrict__ U1c,
                                                    float* __restrict__ U2c) {
  __shared__ float4 sM[48];
  __shared__ float2 xb[2][256];
  const int tid = threadIdx.x;
  const int h   = blockIdx.x >> 8;
  const int s0  = blockIdx.x & 255;
  const int s   = tid;

  if (tid < 48) {
    const int lp  = tid / 24;
    const int rem = tid - lp * 24;
    const int j   = rem >> 3;
    const int q   = rem & 7;
    const int l   = 2 * h + lp;
    float a, bb;
    if (j == 0) {        // M0 = RY(qw[l][q]) * RZ(qw[l-1][124+q])
      a  = qw[l * NW_L + q];
      bb = (l > 0) ? qw[(l - 1) * NW_L + 124 + q] : 0.f;
    } else if (j == 1) { // M1 = RX(44+q) * RY(36+q)
      a  = qw[l * NW_L + 44 + q];
      bb = qw[l * NW_L + 36 + q];
    } else {             // M2 = RZ(88+q) * RX(80+q); RZ dropped at l=3
      a  = (l < 3) ? qw[l * NW_L + 88 + q] : 0.f;
      bb = qw[l * NW_L + 80 + q];
    }
    float sa, ca, sb, cb;
    __sincosf(0.5f * a,  &sa, &ca);
    __sincosf(0.5f * bb, &sb, &cb);
    float4 m;
    if (j == 0)      m = make_float4(ca*cb, -ca*sb, -sa*cb, -sa*sb); // RY*RZ
    else if (j == 1) m = make_float4(ca*cb, -sa*sb, -ca*sb, -sa*cb); // RX*RY
    else             m = make_float4(ca*cb, -sa*cb, -sb*sa, -sb*ca); // RZ*RX
    sM[tid] = m;
  }

  float ar = (s == s0) ? 1.f : 0.f;
  float ai = 0.f;
  const float dzr = D_CRZ.v[2*s];
  const float dzi = D_CRZ.v[2*s+1];
  __syncthreads();

  int pb = 0;
#pragma unroll 1
  for (int lp = 0; lp < 2; ++lp) {
    const int base = lp * 24;
    // M0 block: q=0 -> p7 (xwave), q=1 -> p6 (xwave), q>=2 -> lane p=7-q
#pragma unroll
    for (int q = 0; q < 8; ++q) {
      float4 m = sM[base + q];
      if (q <= 1) { gen_xw(ar, ai, s, 7 - q, m.x, m.y, m.z, m.w, xb[pb]); pb ^= 1; }
      else        gen_lane(ar, ai, s, 7 - q, m.x, m.y, m.z, m.w);
    }
    // CRY block
#pragma unroll
    for (int i = 0; i < 28; ++i) {
      const int pc = 7 - PC[i], pt = 7 - PT[i];
      const float cc = T_CRY.c[i], sc = T_CRY.s[i];
      if (pt == 6) { cry_xw(ar, ai, s, pc, pt, cc, sc, xb[pb]); pb ^= 1; }
      else         cry_lane(ar, ai, s, pc, pt, cc, sc);
    }
    // M1 block
#pragma unroll
    for (int q = 0; q < 8; ++q) {
      float4 m = sM[base + 8 + q];
      if (q <= 1) { gen_xw(ar, ai, s, 7 - q, m.x, m.y, m.z, m.w, xb[pb]); pb ^= 1; }
      else        gen_lane(ar, ai, s, 7 - q, m.x, m.y, m.z, m.w);
    }
    // CRX block
#pragma unroll
    for (int i = 0; i < 28; ++i) {
      const int pc = 7 - PC[i], pt = 7 - PT[i];
      const float cc = T_CRX.c[i], sc = T_CRX.s[i];
      if (pt == 6) { crx_xw(ar, ai, s, pc, pt, cc, sc, xb[pb]); pb ^= 1; }
      else         crx_lane(ar, ai, s, pc, pt, cc, sc);
    }
    // M2 block
#pragma unroll
    for (int q = 0; q < 8; ++q) {
      float4 m = sM[base + 16 + q];
      if (q <= 1) { gen_xw(ar, ai, s, 7 - q, m.x, m.y, m.z, m.w, xb[pb]); pb ^= 1; }
      else        gen_lane(ar, ai, s, 7 - q, m.x, m.y, m.z, m.w);
    }
    // CRZ diagonal (dropped at l==3)
    if (2 * h + lp < 3) {
      const float mr = ar, mi = ai;
      ar = mr*dzr - mi*dzi;
      ai = mr*dzi + mi*dzr;
    }
  }

  // emit: Uc[s0*512 + s*2] = (re, im) — 8B/thread, fully coalesced
  float* Uc = h ? U2c : U1c;
  ((float2*)(Uc + (size_t)s0 * 512))[s] = make_float2(ar, ai);
}

// ---------------- K2: U = U2 * U1 (complex), emit bf16 (R12 verbatim) ----------------
__global__ __launch_bounds__(256) void combine_u(const float* __restrict__ U1c,
                                                 const float* __restrict__ U2c,
                                                 unsigned short* __restrict__ Ubf) {
  __shared__ float2 S2[32 * 16];   // [kk][i]
  __shared__ float2 S1[16 * 33];   // [j][kk] padded
  const int tid = threadIdx.x;
  const int ti  = tid & 15;
  const int tj  = tid >> 4;
  const int bi  = blockIdx.x & 15;
  const int bj  = blockIdx.x >> 4;

  float accr = 0.f, acci = 0.f;
#pragma unroll 1
  for (int kt = 0; kt < 8; ++kt) {
    __syncthreads();
#pragma unroll
    for (int v = 0; v < 2; ++v) {
      const int s = v * 256 + tid;
      const int k  = s >> 4, i = s & 15;
      S2[k * 16 + i] = *(const float2*)(U2c + (size_t)(kt*32 + k) * 512 + (bi*16 + i) * 2);
      const int j2 = s >> 5, k2 = s & 31;
      S1[j2 * 33 + k2] = *(const float2*)(U1c + (size_t)(bj*16 + j2) * 512 + (kt*32 + k2) * 2);
    }
    __syncthreads();
#pragma unroll
    for (int kk = 0; kk < 32; ++kk) {
      const float2 a = S2[kk * 16 + ti];
      const float2 b = S1[tj * 33 + kk];
      accr = fmaf(a.x, b.x, accr);  accr = fmaf(-a.y, b.y, accr);
      acci = fmaf(a.x, b.y, acci);  acci = fmaf(a.y, b.x, acci);
    }
  }
  const int i = bi * 16 + ti, j = bj * 16 + tj;
  Ubf[(size_t)i * 256 + j]         = f2bf(accr);
  Ubf[(size_t)(i + 256) * 256 + j] = f2bf(acci);
}

// ---------------- K3: eval3 — 16 waves/block, 32 rows/wave (R12 verbatim) ----------------
__global__ __launch_bounds__(1024) void eval3(const float* __restrict__ x,
                                              const unsigned short* __restrict__ Ubf,
                                              const float* __restrict__ fcw,
                                              const float* __restrict__ fcb,
                                              float* __restrict__ out) {
  __shared__ unsigned short Xs[16 * 264];   // [col][k] bf16, padded
  __shared__ float Zp[16][16][9];           // [wave][col][9]
  __shared__ float Zf[16][9];
  const int tid  = threadIdx.x;
  const int lane = tid & 63;
  const int w    = tid >> 6;                // 0..15
  const int colbase = blockIdx.x * 16;

  {
    const int k  = tid >> 2;
    const int c4 = (tid & 3) * 4;
    const float4 v = *(const float4*)(x + (size_t)k * NSAMP + colbase + c4);
    Xs[(c4 + 0) * 264 + k] = f2bf(v.x);
    Xs[(c4 + 1) * 264 + k] = f2bf(v.y);
    Xs[(c4 + 2) * 264 + k] = f2bf(v.z);
    Xs[(c4 + 3) * 264 + k] = f2bf(v.w);
  }
  __syncthreads();

  const int quad = lane >> 4;
  const int n    = lane & 15;
  const int rowb = w * 32;

  f32x4 acc[2];
  acc[0] = (f32x4){0.f, 0.f, 0.f, 0.f};
  acc[1] = (f32x4){0.f, 0.f, 0.f, 0.f};

#pragma unroll
  for (int kt = 0; kt < 8; ++kt) {
    const bf16x8 bfrag = *(const bf16x8*)&Xs[n * 264 + kt * 32 + quad * 8];
#pragma unroll
    for (int rt = 0; rt < 2; ++rt) {
      const int row = rowb + rt * 16 + n;
      const bf16x8 afrag = *(const bf16x8*)(Ubf + (size_t)row * 256 + kt * 32 + quad * 8);
      acc[rt] = __builtin_amdgcn_mfma_f32_16x16x32_bf16(afrag, bfrag, acc[rt], 0, 0, 0);
    }
  }

  float za[9];
#pragma unroll
  for (int i = 0; i < 9; ++i) za[i] = 0.f;
  const float m4 = (lane & 32) ? -1.f : 1.f;   // s bit3 = quad bit1
  const float m5 = (lane & 16) ? -1.f : 1.f;   // s bit2 = quad bit0
#pragma unroll
  for (int rt = 0; rt < 2; ++rt) {
#pragma unroll
    for (int reg = 0; reg < 4; ++reg) {
      const float v = acc[rt][reg];
      const float p = v * v;
      za[0] += p;
      za[1] += (w & 4)   ? -p : p;   // q0: s bit7
      za[2] += (w & 2)   ? -p : p;   // q1: s bit6
      za[3] += (w & 1)   ? -p : p;   // q2: s bit5
      za[4] += rt        ? -p : p;   // q3: s bit4
      za[5] = fmaf(m4, p, za[5]);    // q4
      za[6] = fmaf(m5, p, za[6]);    // q5
      za[7] += (reg & 2) ? -p : p;   // q6: s bit1
      za[8] += (reg & 1) ? -p : p;   // q7: s bit0
    }
  }
#pragma unroll
  for (int off = 16; off <= 32; off <<= 1) {
#pragma unroll
    for (int i = 0; i < 9; ++i) za[i] += __shfl_xor(za[i], off, 64);
  }
  if (lane < 16) {
#pragma unroll
    for (int i = 0; i < 9; ++i) Zp[w][lane][i] = za[i];
  }
  __syncthreads();

  if (tid < 144) {
    const int col = tid / 9, q = tid - col * 9;
    float z = 0.f;
#pragma unroll
    for (int ww = 0; ww < 16; ++ww) z += Zp[ww][col][q];
    Zf[col][q] = z;
  }
  __syncthreads();

  if (tid < 112) {
    const int col = tid / 7, oo = tid - col * 7;
    const float inv = 1.f / Zf[col][0];
    float v = fcb[oo];
#pragma unroll
    for (int q = 0; q < 8; ++q)
      v = fmaf(fcw[oo * 8 + q], Zf[col][1 + q] * inv, v);
    out[(size_t)(colbase + col) * 7 + oo] = v;
  }
}

extern "C" void kernel_launch(void* const* d_in, const int* in_sizes, int n_in,
                              void* d_out, int out_size, void* d_ws, size_t ws_size,
                              hipStream_t stream) {
  const float* x   = (const float*)d_in[0];   // [256, 4096]
  const float* qw  = (const float*)d_in[1];   // [4, 132]
  const float* fcw = (const float*)d_in[2];   // [7, 8]
  const float* fcb = (const float*)d_in[3];   // [7]
  float* out = (float*)d_out;                 // [4096, 7]

  float* U1c = (float*)d_ws;                      // 256x256 complex fp32 (512 KB)
  float* U2c = U1c + 256 * 512;                   // 512 KB
  unsigned short* Ubf = (unsigned short*)(U2c + 256 * 512);  // 512x256 bf16 (256 KB)

  hipLaunchKernelGGL(build_half4w, dim3(512), dim3(256),  0, stream, qw, U1c, U2c);
  hipLaunchKernelGGL(combine_u,    dim3(256), dim3(256),  0, stream, U1c, U2c, Ubf);
  hipLaunchKernelGGL(eval3,        dim3(256), dim3(1024), 0, stream, x, Ubf, fcw, fcb, out);
}